// Round 1
// baseline (715.185 us; speedup 1.0000x reference)
//
#include <hip/hip_runtime.h>

#define NLVL 12
#define TBL (1u << 19)
#define BASERES 16
#define MS 524288
#define NRAYS 65536

__global__ __launch_bounds__(256) void sample_kernel(
    const float* __restrict__ rays_o, const float* __restrict__ rays_d,
    const float* __restrict__ t_starts, const float* __restrict__ t_ends,
    const int* __restrict__ ray_indices,
    const float* __restrict__ table_density, const float* __restrict__ table_color,
    const float* __restrict__ w1_density, const float* __restrict__ w2_density,
    const float* __restrict__ w1_color, const float* __restrict__ w2_color,
    float4* __restrict__ ws)
{
    __shared__ float s_w1d[24 * 32];
    __shared__ float s_w1c[24 * 32];
    __shared__ float s_w2d[32];
    __shared__ float s_w2c[96];
    const int tid = threadIdx.x;
    for (int i = tid; i < 24 * 32; i += 256) {
        s_w1d[i] = w1_density[i];
        s_w1c[i] = w1_color[i];
    }
    if (tid < 32) s_w2d[tid] = w2_density[tid];
    if (tid < 96) s_w2c[tid] = w2_color[tid];
    __syncthreads();

    const int i = blockIdx.x * 256 + tid;
    if (i >= MS) return;

    const int r = ray_indices[i];
    const float ts = t_starts[i];
    const float te = t_ends[i];
    const float tmid = 0.5f * (ts + te);

    float x01[3];
#pragma unroll
    for (int d = 0; d < 3; ++d) {
        float x = rays_o[r * 3 + d] + rays_d[r * 3 + d] * tmid;
        float v = (x + 1.0f) * 0.5f;
        x01[d] = fminf(fmaxf(v, 0.0f), 1.0f - 1e-6f);
    }

    float fd[24], fc[24];
#pragma unroll
    for (int k = 0; k < 24; ++k) { fd[k] = 0.0f; fc[k] = 0.0f; }

#pragma unroll
    for (int l = 0; l < NLVL; ++l) {
        const float res = (float)(BASERES << l);
        unsigned p0[3];
        float frac[3];
#pragma unroll
        for (int d = 0; d < 3; ++d) {
            float pos = x01[d] * res;
            float f0 = floorf(pos);
            frac[d] = pos - f0;
            p0[d] = (unsigned)f0;
        }
        const float2* td = (const float2*)table_density + (size_t)l * TBL;
        const float2* tc = (const float2*)table_color + (size_t)l * TBL;
        float a0 = 0.f, a1 = 0.f, b0 = 0.f, b1 = 0.f;
#pragma unroll
        for (int c = 0; c < 8; ++c) {
            const unsigned bx = c & 1u, by = (c >> 1) & 1u, bz = (c >> 2) & 1u;
            const unsigned cx = p0[0] + bx;
            const unsigned cy = p0[1] + by;
            const unsigned cz = p0[2] + bz;
            const unsigned h = cx * 1u ^ cy * 2654435761u ^ cz * 805459861u;
            const unsigned idx = h & (TBL - 1u);
            const float w = (bx ? frac[0] : 1.0f - frac[0]) *
                            (by ? frac[1] : 1.0f - frac[1]) *
                            (bz ? frac[2] : 1.0f - frac[2]);
            const float2 vd = td[idx];
            const float2 vc = tc[idx];
            a0 += w * vd.x; a1 += w * vd.y;
            b0 += w * vc.x; b1 += w * vc.y;
        }
        fd[2 * l + 0] = a0; fd[2 * l + 1] = a1;
        fc[2 * l + 0] = b0; fc[2 * l + 1] = b1;
    }

    // density MLP: relu(fd @ w1d) @ w2d -> exp
    float outd = 0.0f;
#pragma unroll
    for (int j = 0; j < 32; ++j) {
        float h = 0.0f;
#pragma unroll
        for (int k = 0; k < 24; ++k) h += fd[k] * s_w1d[k * 32 + j];
        h = fmaxf(h, 0.0f);
        outd += h * s_w2d[j];
    }
    const float sigma = __expf(outd);

    // color MLP: relu(fc @ w1c) @ w2c -> sigmoid
    float o0 = 0.0f, o1 = 0.0f, o2 = 0.0f;
#pragma unroll
    for (int j = 0; j < 32; ++j) {
        float h = 0.0f;
#pragma unroll
        for (int k = 0; k < 24; ++k) h += fc[k] * s_w1c[k * 32 + j];
        h = fmaxf(h, 0.0f);
        o0 += h * s_w2c[j * 3 + 0];
        o1 += h * s_w2c[j * 3 + 1];
        o2 += h * s_w2c[j * 3 + 2];
    }
    const float r0 = 1.0f / (1.0f + __expf(-o0));
    const float r1 = 1.0f / (1.0f + __expf(-o1));
    const float r2 = 1.0f / (1.0f + __expf(-o2));

    const float s = sigma * (te - ts);
    ws[i] = make_float4(s, r0, r1, r2);
}

__global__ __launch_bounds__(256) void render_kernel(
    const int* __restrict__ ray_indices, const float4* __restrict__ ws,
    float* __restrict__ out)
{
    const int r = blockIdx.x * 256 + threadIdx.x;
    if (r >= NRAYS) return;

    // lower_bound over sorted ray_indices
    int lo = 0, hi = MS;
    while (lo < hi) { int mid = (lo + hi) >> 1; if (ray_indices[mid] < r) lo = mid + 1; else hi = mid; }
    const int start = lo;
    hi = MS;
    while (lo < hi) { int mid = (lo + hi) >> 1; if (ray_indices[mid] < r + 1) lo = mid + 1; else hi = mid; }
    const int end = lo;

    float runsum = 0.0f, acc = 0.0f, c0 = 0.0f, c1 = 0.0f, c2 = 0.0f;
    for (int i = start; i < end; ++i) {
        const float4 v = ws[i];
        const float alpha = 1.0f - __expf(-v.x);
        const float w = __expf(-runsum) * alpha;
        c0 += w * v.y; c1 += w * v.z; c2 += w * v.w;
        acc += w;
        runsum += v.x;
    }
    const float bg = 1.0f - acc;
    c0 = fminf(fmaxf(c0 + bg, 0.0f), 1.0f);
    c1 = fminf(fmaxf(c1 + bg, 0.0f), 1.0f);
    c2 = fminf(fmaxf(c2 + bg, 0.0f), 1.0f);
    const float a = fminf(fmaxf(acc, 0.0f), 1.0f);
    out[r * 4 + 0] = c0;
    out[r * 4 + 1] = c1;
    out[r * 4 + 2] = c2;
    out[r * 4 + 3] = a;
}

extern "C" void kernel_launch(void* const* d_in, const int* in_sizes, int n_in,
                              void* d_out, int out_size, void* d_ws, size_t ws_size,
                              hipStream_t stream) {
    (void)in_sizes; (void)n_in; (void)out_size; (void)ws_size;
    const float* rays_o        = (const float*)d_in[0];
    const float* rays_d        = (const float*)d_in[1];
    const float* t_starts      = (const float*)d_in[2];
    const float* t_ends        = (const float*)d_in[3];
    const int*   ray_indices   = (const int*)d_in[4];
    const float* table_density = (const float*)d_in[5];
    const float* table_color   = (const float*)d_in[6];
    const float* w1_density    = (const float*)d_in[7];
    const float* w2_density    = (const float*)d_in[8];
    const float* w1_color      = (const float*)d_in[9];
    const float* w2_color      = (const float*)d_in[10];
    float* out = (float*)d_out;
    float4* ws = (float4*)d_ws;

    sample_kernel<<<MS / 256, 256, 0, stream>>>(
        rays_o, rays_d, t_starts, t_ends, ray_indices,
        table_density, table_color, w1_density, w2_density, w1_color, w2_color, ws);
    render_kernel<<<NRAYS / 256, 256, 0, stream>>>(ray_indices, ws, out);
}

// Round 2
// 249.848 us; speedup vs baseline: 2.8625x; 2.8625x over previous
//
#include <hip/hip_runtime.h>
#include <hip/hip_fp16.h>

#define NLVL 12
#define TBL (1u << 19)
#define BASERES 16
#define MS 524288
#define NRAYS 65536

#define PACK_ENTRIES (NLVL * TBL)                       // 6291456
#define PACKED_BYTES ((size_t)PACK_ENTRIES * 8)         // 50331648
#define FEATS_BYTES  ((size_t)NLVL * MS * 8)            // 50331648
#define SAMP_BYTES   ((size_t)MS * 16)                  // 8388608
#define WS_NEEDED    (PACKED_BYTES + FEATS_BYTES + SAMP_BYTES)

__device__ __forceinline__ void unpack4(uint2 v, float& a, float& b, float& c, float& d) {
    __half2 lo = *reinterpret_cast<const __half2*>(&v.x);
    __half2 hi = *reinterpret_cast<const __half2*>(&v.y);
    float2 f0 = __half22float2(lo);
    float2 f1 = __half22float2(hi);
    a = f0.x; b = f0.y; c = f1.x; d = f1.y;
}

// ---------------- fast path ----------------

__global__ __launch_bounds__(256) void pack_kernel(
    const float2* __restrict__ td, const float2* __restrict__ tc,
    uint2* __restrict__ packed)
{
    const int i = blockIdx.x * 256 + threadIdx.x;
    const float2 d = td[i];
    const float2 c = tc[i];
    union { __half h[4]; uint2 u; } o;
    o.h[0] = __float2half_rn(d.x);
    o.h[1] = __float2half_rn(d.y);
    o.h[2] = __float2half_rn(c.x);
    o.h[3] = __float2half_rn(c.y);
    packed[i] = o.u;
}

__global__ __launch_bounds__(256) void encode_kernel(
    const float* __restrict__ rays_o, const float* __restrict__ rays_d,
    const float* __restrict__ t_starts, const float* __restrict__ t_ends,
    const int* __restrict__ ray_indices,
    const uint2* __restrict__ packed, uint2* __restrict__ feats)
{
    const int bid = blockIdx.x;
    const int level = bid >> 11;                 // 2048 blocks per level, level-major
    const int i = ((bid & 2047) << 8) + threadIdx.x;

    const int r = ray_indices[i];
    const float tmid = 0.5f * (t_starts[i] + t_ends[i]);
    const float res = (float)(BASERES << level);

    unsigned p0[3];
    float frac[3];
#pragma unroll
    for (int d = 0; d < 3; ++d) {
        float x = rays_o[r * 3 + d] + rays_d[r * 3 + d] * tmid;
        float v = (x + 1.0f) * 0.5f;
        v = fminf(fmaxf(v, 0.0f), 1.0f - 1e-6f);
        float pos = v * res;
        float f0 = floorf(pos);
        frac[d] = pos - f0;
        p0[d] = (unsigned)f0;
    }

    const uint2* tab = packed + (size_t)level * TBL;
    float a0 = 0.f, a1 = 0.f, a2 = 0.f, a3 = 0.f;
#pragma unroll
    for (int c = 0; c < 8; ++c) {
        const unsigned bx = c & 1u, by = (c >> 1) & 1u, bz = (c >> 2) & 1u;
        const unsigned h = (p0[0] + bx) * 1u ^ (p0[1] + by) * 2654435761u ^ (p0[2] + bz) * 805459861u;
        const unsigned idx = h & (TBL - 1u);
        const float w = (bx ? frac[0] : 1.0f - frac[0]) *
                        (by ? frac[1] : 1.0f - frac[1]) *
                        (bz ? frac[2] : 1.0f - frac[2]);
        float d0, d1, c0, c1;
        unpack4(tab[idx], d0, d1, c0, c1);
        a0 += w * d0; a1 += w * d1; a2 += w * c0; a3 += w * c1;
    }

    union { __half h[4]; uint2 u; } o;
    o.h[0] = __float2half_rn(a0);
    o.h[1] = __float2half_rn(a1);
    o.h[2] = __float2half_rn(a2);
    o.h[3] = __float2half_rn(a3);
    feats[(size_t)level * MS + i] = o.u;
}

__global__ __launch_bounds__(256) void mlp_kernel(
    const float* __restrict__ t_starts, const float* __restrict__ t_ends,
    const uint2* __restrict__ feats,
    const float* __restrict__ w1_density, const float* __restrict__ w2_density,
    const float* __restrict__ w1_color, const float* __restrict__ w2_color,
    float4* __restrict__ samp)
{
    __shared__ float s_w1d[24 * 32];
    __shared__ float s_w1c[24 * 32];
    __shared__ float s_w2d[32];
    __shared__ float s_w2c[96];
    const int tid = threadIdx.x;
    for (int k = tid; k < 24 * 32; k += 256) {
        s_w1d[k] = w1_density[k];
        s_w1c[k] = w1_color[k];
    }
    if (tid < 32) s_w2d[tid] = w2_density[tid];
    if (tid < 96) s_w2c[tid] = w2_color[tid];
    __syncthreads();

    const int i = blockIdx.x * 256 + tid;

    float fd[24], fc[24];
#pragma unroll
    for (int l = 0; l < NLVL; ++l) {
        float d0, d1, c0, c1;
        unpack4(feats[(size_t)l * MS + i], d0, d1, c0, c1);
        fd[2 * l + 0] = d0; fd[2 * l + 1] = d1;
        fc[2 * l + 0] = c0; fc[2 * l + 1] = c1;
    }

    float outd = 0.0f;
#pragma unroll
    for (int j = 0; j < 32; ++j) {
        float h = 0.0f;
#pragma unroll
        for (int k = 0; k < 24; ++k) h += fd[k] * s_w1d[k * 32 + j];
        h = fmaxf(h, 0.0f);
        outd += h * s_w2d[j];
    }
    const float sigma = __expf(outd);

    float o0 = 0.0f, o1 = 0.0f, o2 = 0.0f;
#pragma unroll
    for (int j = 0; j < 32; ++j) {
        float h = 0.0f;
#pragma unroll
        for (int k = 0; k < 24; ++k) h += fc[k] * s_w1c[k * 32 + j];
        h = fmaxf(h, 0.0f);
        o0 += h * s_w2c[j * 3 + 0];
        o1 += h * s_w2c[j * 3 + 1];
        o2 += h * s_w2c[j * 3 + 2];
    }
    const float r0 = 1.0f / (1.0f + __expf(-o0));
    const float r1 = 1.0f / (1.0f + __expf(-o1));
    const float r2 = 1.0f / (1.0f + __expf(-o2));

    const float ts = t_starts[i];
    const float te = t_ends[i];
    const float sigexp = sigma * (te - ts);
    samp[i] = make_float4(sigexp, r0, r1, r2);
}

// ---------------- fallback path (round-1, proven correct) ----------------

__global__ __launch_bounds__(256) void sample_kernel(
    const float* __restrict__ rays_o, const float* __restrict__ rays_d,
    const float* __restrict__ t_starts, const float* __restrict__ t_ends,
    const int* __restrict__ ray_indices,
    const float* __restrict__ table_density, const float* __restrict__ table_color,
    const float* __restrict__ w1_density, const float* __restrict__ w2_density,
    const float* __restrict__ w1_color, const float* __restrict__ w2_color,
    float4* __restrict__ ws)
{
    __shared__ float s_w1d[24 * 32];
    __shared__ float s_w1c[24 * 32];
    __shared__ float s_w2d[32];
    __shared__ float s_w2c[96];
    const int tid = threadIdx.x;
    for (int i = tid; i < 24 * 32; i += 256) {
        s_w1d[i] = w1_density[i];
        s_w1c[i] = w1_color[i];
    }
    if (tid < 32) s_w2d[tid] = w2_density[tid];
    if (tid < 96) s_w2c[tid] = w2_color[tid];
    __syncthreads();

    const int i = blockIdx.x * 256 + tid;
    if (i >= MS) return;

    const int r = ray_indices[i];
    const float ts = t_starts[i];
    const float te = t_ends[i];
    const float tmid = 0.5f * (ts + te);

    float x01[3];
#pragma unroll
    for (int d = 0; d < 3; ++d) {
        float x = rays_o[r * 3 + d] + rays_d[r * 3 + d] * tmid;
        float v = (x + 1.0f) * 0.5f;
        x01[d] = fminf(fmaxf(v, 0.0f), 1.0f - 1e-6f);
    }

    float fd[24], fc[24];
#pragma unroll
    for (int k = 0; k < 24; ++k) { fd[k] = 0.0f; fc[k] = 0.0f; }

#pragma unroll
    for (int l = 0; l < NLVL; ++l) {
        const float res = (float)(BASERES << l);
        unsigned p0[3];
        float frac[3];
#pragma unroll
        for (int d = 0; d < 3; ++d) {
            float pos = x01[d] * res;
            float f0 = floorf(pos);
            frac[d] = pos - f0;
            p0[d] = (unsigned)f0;
        }
        const float2* td = (const float2*)table_density + (size_t)l * TBL;
        const float2* tc = (const float2*)table_color + (size_t)l * TBL;
        float a0 = 0.f, a1 = 0.f, b0 = 0.f, b1 = 0.f;
#pragma unroll
        for (int c = 0; c < 8; ++c) {
            const unsigned bx = c & 1u, by = (c >> 1) & 1u, bz = (c >> 2) & 1u;
            const unsigned h = (p0[0] + bx) * 1u ^ (p0[1] + by) * 2654435761u ^ (p0[2] + bz) * 805459861u;
            const unsigned idx = h & (TBL - 1u);
            const float w = (bx ? frac[0] : 1.0f - frac[0]) *
                            (by ? frac[1] : 1.0f - frac[1]) *
                            (bz ? frac[2] : 1.0f - frac[2]);
            const float2 vd = td[idx];
            const float2 vc = tc[idx];
            a0 += w * vd.x; a1 += w * vd.y;
            b0 += w * vc.x; b1 += w * vc.y;
        }
        fd[2 * l + 0] = a0; fd[2 * l + 1] = a1;
        fc[2 * l + 0] = b0; fc[2 * l + 1] = b1;
    }

    float outd = 0.0f;
#pragma unroll
    for (int j = 0; j < 32; ++j) {
        float h = 0.0f;
#pragma unroll
        for (int k = 0; k < 24; ++k) h += fd[k] * s_w1d[k * 32 + j];
        h = fmaxf(h, 0.0f);
        outd += h * s_w2d[j];
    }
    const float sigma = __expf(outd);

    float o0 = 0.0f, o1 = 0.0f, o2 = 0.0f;
#pragma unroll
    for (int j = 0; j < 32; ++j) {
        float h = 0.0f;
#pragma unroll
        for (int k = 0; k < 24; ++k) h += fc[k] * s_w1c[k * 32 + j];
        h = fmaxf(h, 0.0f);
        o0 += h * s_w2c[j * 3 + 0];
        o1 += h * s_w2c[j * 3 + 1];
        o2 += h * s_w2c[j * 3 + 2];
    }
    const float r0 = 1.0f / (1.0f + __expf(-o0));
    const float r1 = 1.0f / (1.0f + __expf(-o1));
    const float r2 = 1.0f / (1.0f + __expf(-o2));

    const float s = sigma * (te - ts);
    ws[i] = make_float4(s, r0, r1, r2);
}

// ---------------- render (shared) ----------------

__global__ __launch_bounds__(256) void render_kernel(
    const int* __restrict__ ray_indices, const float4* __restrict__ samp,
    float* __restrict__ out)
{
    const int r = blockIdx.x * 256 + threadIdx.x;
    if (r >= NRAYS) return;

    int lo = 0, hi = MS;
    while (lo < hi) { int mid = (lo + hi) >> 1; if (ray_indices[mid] < r) lo = mid + 1; else hi = mid; }
    const int start = lo;
    hi = MS;
    while (lo < hi) { int mid = (lo + hi) >> 1; if (ray_indices[mid] < r + 1) lo = mid + 1; else hi = mid; }
    const int end = lo;

    float runsum = 0.0f, acc = 0.0f, c0 = 0.0f, c1 = 0.0f, c2 = 0.0f;
    for (int i = start; i < end; ++i) {
        const float4 v = samp[i];
        const float alpha = 1.0f - __expf(-v.x);
        const float w = __expf(-runsum) * alpha;
        c0 += w * v.y; c1 += w * v.z; c2 += w * v.w;
        acc += w;
        runsum += v.x;
    }
    const float bg = 1.0f - acc;
    c0 = fminf(fmaxf(c0 + bg, 0.0f), 1.0f);
    c1 = fminf(fmaxf(c1 + bg, 0.0f), 1.0f);
    c2 = fminf(fmaxf(c2 + bg, 0.0f), 1.0f);
    const float a = fminf(fmaxf(acc, 0.0f), 1.0f);
    out[r * 4 + 0] = c0;
    out[r * 4 + 1] = c1;
    out[r * 4 + 2] = c2;
    out[r * 4 + 3] = a;
}

extern "C" void kernel_launch(void* const* d_in, const int* in_sizes, int n_in,
                              void* d_out, int out_size, void* d_ws, size_t ws_size,
                              hipStream_t stream) {
    (void)in_sizes; (void)n_in; (void)out_size;
    const float* rays_o        = (const float*)d_in[0];
    const float* rays_d        = (const float*)d_in[1];
    const float* t_starts      = (const float*)d_in[2];
    const float* t_ends        = (const float*)d_in[3];
    const int*   ray_indices   = (const int*)d_in[4];
    const float* table_density = (const float*)d_in[5];
    const float* table_color   = (const float*)d_in[6];
    const float* w1_density    = (const float*)d_in[7];
    const float* w2_density    = (const float*)d_in[8];
    const float* w1_color      = (const float*)d_in[9];
    const float* w2_color      = (const float*)d_in[10];
    float* out = (float*)d_out;

    if (ws_size >= WS_NEEDED) {
        char* base = (char*)d_ws;
        uint2*  packed = (uint2*)base;
        uint2*  feats  = (uint2*)(base + PACKED_BYTES);
        float4* samp   = (float4*)(base + PACKED_BYTES + FEATS_BYTES);

        pack_kernel<<<PACK_ENTRIES / 256, 256, 0, stream>>>(
            (const float2*)table_density, (const float2*)table_color, packed);
        encode_kernel<<<NLVL * (MS / 256), 256, 0, stream>>>(
            rays_o, rays_d, t_starts, t_ends, ray_indices, packed, feats);
        mlp_kernel<<<MS / 256, 256, 0, stream>>>(
            t_starts, t_ends, feats, w1_density, w2_density, w1_color, w2_color, samp);
        render_kernel<<<NRAYS / 256, 256, 0, stream>>>(ray_indices, samp, out);
    } else {
        float4* samp = (float4*)d_ws;
        sample_kernel<<<MS / 256, 256, 0, stream>>>(
            rays_o, rays_d, t_starts, t_ends, ray_indices,
            table_density, table_color, w1_density, w2_density, w1_color, w2_color, samp);
        render_kernel<<<NRAYS / 256, 256, 0, stream>>>(ray_indices, samp, out);
    }
}